// Round 8
// baseline (116.931 us; speedup 1.0000x reference)
//
#include <hip/hip_runtime.h>

namespace {
constexpr int XP = 264;        // f16 pixel pitch (= 33 chunks of 16B, incl. zero pad c=256..263)
constexpr int XR = 18 * XP;    // halo row pitch in f16 (= 9504 B)
constexpr int EWP = 148;       // ew pixel pitch (floats)
constexpr size_t SLAB = (size_t)67 * XR;   // f16 per (b,strip) slab: 67 rows (1 + 64 + 1 halo + 1 spare)

typedef _Float16 h2 __attribute__((ext_vector_type(2)));
typedef _Float16 h8 __attribute__((ext_vector_type(8)));
typedef float f32x4 __attribute__((ext_vector_type(4)));

__device__ __forceinline__ h2 pkrtz(float a, float b) {
  return __builtin_bit_cast(h2, __builtin_amdgcn_cvt_pkrtz(a, b));
}

__device__ __forceinline__ void load_lds16(const void* g, void* l) {
  __builtin_amdgcn_global_load_lds(
      (const __attribute__((address_space(1))) void*)g,
      (__attribute__((address_space(3))) void*)l, 16, 0, 0);
}

#if __has_builtin(__builtin_amdgcn_fdot2)
#define HAS_FDOT2 1
#else
#define HAS_FDOT2 0
#endif

// ---- prep: W12 = W1*W2 packed in f16 B-frag order, b12 = b1*W2 + b2 ----
__global__ __launch_bounds__(256) void prep_w12(
    const float* __restrict__ W1, const float* __restrict__ b1,
    const float* __restrict__ W2, const float* __restrict__ b2,
    _Float16* __restrict__ pack, float* __restrict__ b12)
{
  const int t = threadIdx.x;
  const int T = blockIdx.x;
  if (T < 9) {
    __shared__ float sw2[64 * 16];
    for (int i = t; i < 1024; i += 256) {
      int d = i >> 4, n = i & 15;
      sw2[i] = W2[d * 144 + T * 16 + n];
    }
    __syncthreads();
    const int c = t;
    float acc[16];
#pragma unroll
    for (int n = 0; n < 16; ++n) acc[n] = 0.f;
    for (int d = 0; d < 64; d += 4) {
      float4 w1 = *(const float4*)(W1 + c * 64 + d);
#pragma unroll
      for (int dd = 0; dd < 4; ++dd) {
        float a = (dd == 0) ? w1.x : (dd == 1) ? w1.y : (dd == 2) ? w1.z : w1.w;
        const float* r = &sw2[(d + dd) * 16];
#pragma unroll
        for (int n = 0; n < 16; ++n) acc[n] += a * r[n];
      }
    }
    int s = c >> 5, q = (c >> 3) & 3, j = c & 7;
#pragma unroll
    for (int n = 0; n < 16; ++n)
      pack[(((T * 8 + s) * 64 + q * 16 + n) << 3) + j] = (_Float16)acc[n];
  } else if (t < 144) {
    float bb = b2[t];
    for (int d = 0; d < 64; ++d) bb += b1[d] * W2[d * 144 + t];
    b12[t] = bb;
  }
}

// ---- prep_xpad: x fp32 -> f16, pre-padded halo slabs, LDS-layout-identical ----
// xpad[(b*4+strip)][s in 0..66][j in 0..17][264], s holds source row s-1 (rows 0,65 = zeros)
__global__ __launch_bounds__(256) void prep_xpad(
    const float* __restrict__ x, _Float16* __restrict__ xpad)
{
  const int t = threadIdx.x;
  const int blk = blockIdx.x;               // (b*4+strip)*66 + s
  const int s = blk % 66;
  const int bs = blk / 66;
  const int b = bs >> 2, strip = bs & 3;
  const int w0 = strip * 16;
  const int hsrc = s - 1;
  const bool rowok = (unsigned)hsrc < 64u;
  _Float16* dst0 = xpad + (SLAB * bs) + (size_t)s * XR;
  for (int idx = t; idx < 594; idx += 256) {  // 18 px * 33 chunks
    int j = idx / 33, cc = idx % 33;
    int w = w0 + j - 1;
    uint4 o = make_uint4(0u, 0u, 0u, 0u);
    if (rowok && cc < 32 && (unsigned)w < 64u) {
      const float* src = x + (((size_t)(b * 64 + hsrc) * 64 + w) << 8) + cc * 8;
      float4 v0 = *(const float4*)(src);
      float4 v1 = *(const float4*)(src + 4);
      o.x = __builtin_bit_cast(unsigned, pkrtz(v0.x, v0.y));
      o.y = __builtin_bit_cast(unsigned, pkrtz(v0.z, v0.w));
      o.z = __builtin_bit_cast(unsigned, pkrtz(v1.x, v1.y));
      o.w = __builtin_bit_cast(unsigned, pkrtz(v1.z, v1.w));
    }
    *(uint4*)(dst0 + j * XP + cc * 8) = o;
  }
}

// ---- fused (DMA staging): global_load_lds halo -> MFMA GEMM -> dot2 involution ----
__global__ __launch_bounds__(256) void invo_fused_dma(
    const _Float16* __restrict__ xpad,
    const _Float16* __restrict__ pack,
    const float* __restrict__ b12g,
    float* __restrict__ out)
{
  __shared__ __align__(16) _Float16 xg[1792 * 8];   // 28,672 B (3 rows + 10-chunk spill)
  __shared__ float ew[16 * EWP];                    //  9,472 B

  const int t = threadIdx.x;
  const int blk = blockIdx.x;               // XCD swizzle: b = blk & 7
  const int b = blk & 7;
  const int r_ = blk >> 3;
  const int strip = r_ & 3;
  const int h = r_ >> 2;
  const int w0 = strip * 16;
  const int pix0 = ((b << 6) + h) * 64 + w0;
  const int wave = t >> 6, lane = t & 63;

  // ---- stage: 28 wave-DMAs, identical global/LDS offsets (rows h..h+2 of the slab) ----
  {
    const char* gsrc = (const char*)(xpad + SLAB * (b * 4 + strip) + (size_t)h * XR);
    char* lds = (char*)xg;
    const int base = wave * 7168 + lane * 16;
#pragma unroll
    for (int i = 0; i < 7; ++i) {
      int off = base + i * 1024;
      load_lds16(gsrc + off, lds + off);
    }
  }
  __syncthreads();

  // ---- GEMM via MFMA: e[p][e] = b12[e] + sum_c x[p][c] * W12[c][e] ----
  {
    const int q = lane >> 4, m = lane & 15;
    h8 A[8];
    const _Float16* arow = &xg[XR + (m + 1) * XP + q * 8];
#pragma unroll
    for (int s = 0; s < 8; ++s)
      A[s] = *(const h8*)(arow + s * 32);
    for (int T = wave; T < 9; T += 4) {
      f32x4 acc = {0.f, 0.f, 0.f, 0.f};
      const h8* bp = (const h8*)pack + (T * 8) * 64 + lane;
#pragma unroll
      for (int s = 0; s < 8; ++s)
        acc = __builtin_amdgcn_mfma_f32_16x16x32_f16(A[s], bp[s * 64], acc, 0, 0, 0);
      float bb = b12g[T * 16 + m];            // D col = lane&15
#pragma unroll
      for (int r = 0; r < 4; ++r)
        ew[(q * 4 + r) * EWP + T * 16 + m] = acc[r] + bb;   // D row = q*4+r = pixel
    }
  }
  __syncthreads();

  // ---- involution: thread=(p,g); 18x ds_read_b128, v_dot2_f32_f16 inner ----
  {
    const int p = t >> 4, g = t & 15;
    float ewr[9];
#pragma unroll
    for (int k = 0; k < 9; ++k) ewr[k] = ew[p * EWP + g * 9 + k];
    h2 wp[8];
#pragma unroll
    for (int m = 0; m < 8; ++m)
      wp[m] = pkrtz(ewr[m], ewr[m + 1]);
    const float w8 = ewr[8], wb0 = ewr[0];
    const int g144 = g * 144;
    const int pbase = p * XP;
    float res[16];
#pragma unroll
    for (int gc = 0; gc < 16; ++gc) res[gc] = 0.f;
#pragma unroll
    for (int j = 0; j < 18; ++j) {
      int f = g144 + j * 8;
      int tap = f >> 8;
      int ch = f & 255;
      int di = (tap * 86) >> 8;
      int dj = tap - 3 * di;
      uint4 dv = *(const uint4*)(&xg[di * XR + (p + dj) * XP + ch]);
      h2 v[4];
      v[0] = __builtin_bit_cast(h2, dv.x);
      v[1] = __builtin_bit_cast(h2, dv.y);
      v[2] = __builtin_bit_cast(h2, dv.z);
      v[3] = __builtin_bit_cast(h2, dv.w);
#pragma unroll
      for (int i = 0; i < 4; ++i) {
        const int u = j * 8 + 2 * i;
        const int m = u % 9;
        if (m == 8) {
          res[u / 9]     += (float)v[i][0] * w8;
          res[u / 9 + 1] += (float)v[i][1] * wb0;
        } else {
#if HAS_FDOT2
          res[u / 9] = __builtin_amdgcn_fdot2(v[i], wp[m], res[u / 9], false);
#else
          res[u / 9] += (float)v[i][0] * ewr[m] + (float)v[i][1] * ewr[m + 1];
#endif
        }
      }
    }
    float* orow = out + (size_t)(pix0 + p) * 256 + (g << 4);
    *(float4*)(orow + 0)  = make_float4(res[0],  res[1],  res[2],  res[3]);
    *(float4*)(orow + 4)  = make_float4(res[4],  res[5],  res[6],  res[7]);
    *(float4*)(orow + 8)  = make_float4(res[8],  res[9],  res[10], res[11]);
    *(float4*)(orow + 12) = make_float4(res[12], res[13], res[14], res[15]);
  }
}

// ---- fallback: R7 fused (inline staging) if ws too small for xpad ----
__global__ __launch_bounds__(256) void invo_fused(
    const float* __restrict__ x, const _Float16* __restrict__ pack,
    const float* __restrict__ b12g, float* __restrict__ out)
{
  __shared__ __align__(16) _Float16 xg[3 * XR];
  __shared__ float ew[16 * EWP];
  const int t = threadIdx.x;
  const int blk = blockIdx.x;
  const int b = blk & 7;
  const int r_ = blk >> 3;
  const int strip = r_ & 3;
  const int h = r_ >> 2;
  const int w0 = strip * 16;
  const int pix0 = ((b << 6) + h) * 64 + w0;
  for (int idx = t; idx < 3 * 18 * 64; idx += 256) {
    int c4 = (idx & 63) << 2;
    int pr = idx >> 6;
    int r = (pr >= 36) ? 2 : (pr >= 18 ? 1 : 0);
    int j = pr - r * 18;
    int hh = h + r - 1, ww = w0 + j - 1;
    float4 v = make_float4(0.f, 0.f, 0.f, 0.f);
    if (((unsigned)hh < 64u) && ((unsigned)ww < 64u))
      v = *(const float4*)(x + ((((b << 6) + hh) << 6) + ww) * 256 + c4);
    h2 lo = pkrtz(v.x, v.y), hi = pkrtz(v.z, v.w);
    uint2 u;
    u.x = __builtin_bit_cast(unsigned, lo);
    u.y = __builtin_bit_cast(unsigned, hi);
    *(uint2*)(&xg[r * XR + j * XP + c4]) = u;
  }
  __syncthreads();
  {
    const int wave = t >> 6, lane = t & 63;
    const int q = lane >> 4, m = lane & 15;
    h8 A[8];
    const _Float16* arow = &xg[XR + (m + 1) * XP + q * 8];
#pragma unroll
    for (int s = 0; s < 8; ++s) A[s] = *(const h8*)(arow + s * 32);
    for (int T = wave; T < 9; T += 4) {
      f32x4 acc = {0.f, 0.f, 0.f, 0.f};
      const h8* bp = (const h8*)pack + (T * 8) * 64 + lane;
#pragma unroll
      for (int s = 0; s < 8; ++s)
        acc = __builtin_amdgcn_mfma_f32_16x16x32_f16(A[s], bp[s * 64], acc, 0, 0, 0);
      float bb = b12g[T * 16 + m];
#pragma unroll
      for (int r = 0; r < 4; ++r)
        ew[(q * 4 + r) * EWP + T * 16 + m] = acc[r] + bb;
    }
  }
  __syncthreads();
  {
    const int p = t >> 4, g = t & 15;
    float ewr[9];
#pragma unroll
    for (int k = 0; k < 9; ++k) ewr[k] = ew[p * EWP + g * 9 + k];
    h2 wp[8];
#pragma unroll
    for (int m = 0; m < 8; ++m) wp[m] = pkrtz(ewr[m], ewr[m + 1]);
    const float w8 = ewr[8], wb0 = ewr[0];
    const int g144 = g * 144;
    const int pbase = p * XP;
    float res[16];
#pragma unroll
    for (int gc = 0; gc < 16; ++gc) res[gc] = 0.f;
#pragma unroll
    for (int j = 0; j < 18; ++j) {
      int f = g144 + j * 8;
      int tap = f >> 8;
      int ch = f & 255;
      int di = (tap * 86) >> 8;
      int dj = tap - 3 * di;
      uint4 dv = *(const uint4*)(&xg[di * XR + (p + dj) * XP + ch]);
      h2 v[4];
      v[0] = __builtin_bit_cast(h2, dv.x);
      v[1] = __builtin_bit_cast(h2, dv.y);
      v[2] = __builtin_bit_cast(h2, dv.z);
      v[3] = __builtin_bit_cast(h2, dv.w);
#pragma unroll
      for (int i = 0; i < 4; ++i) {
        const int u = j * 8 + 2 * i;
        const int m = u % 9;
        if (m == 8) {
          res[u / 9]     += (float)v[i][0] * w8;
          res[u / 9 + 1] += (float)v[i][1] * wb0;
        } else {
#if HAS_FDOT2
          res[u / 9] = __builtin_amdgcn_fdot2(v[i], wp[m], res[u / 9], false);
#else
          res[u / 9] += (float)v[i][0] * ewr[m] + (float)v[i][1] * ewr[m + 1];
#endif
        }
      }
    }
    float* orow = out + (size_t)(pix0 + p) * 256 + (g << 4);
    *(float4*)(orow + 0)  = make_float4(res[0],  res[1],  res[2],  res[3]);
    *(float4*)(orow + 4)  = make_float4(res[4],  res[5],  res[6],  res[7]);
    *(float4*)(orow + 8)  = make_float4(res[8],  res[9],  res[10], res[11]);
    *(float4*)(orow + 12) = make_float4(res[12], res[13], res[14], res[15]);
  }
}
} // namespace

extern "C" void kernel_launch(void* const* d_in, const int* in_sizes, int n_in,
                              void* d_out, int out_size, void* d_ws, size_t ws_size,
                              hipStream_t stream) {
  const float* x  = (const float*)d_in[0];
  const float* W1 = (const float*)d_in[1];
  const float* b1 = (const float*)d_in[2];
  const float* W2 = (const float*)d_in[3];
  const float* b2 = (const float*)d_in[4];
  float* out = (float*)d_out;
  _Float16* pack = (_Float16*)d_ws;                        // 73,728 B
  float* b12 = (float*)((char*)d_ws + 73728);              // 576 B
  _Float16* xpad = (_Float16*)((char*)d_ws + 131072);      // 32 slabs * 636,768 B
  const size_t ENEED = 131072 + (size_t)32 * SLAB * 2;     // ~20.5 MB
  prep_w12<<<10, 256, 0, stream>>>(W1, b1, W2, b2, pack, b12);
  if (ws_size >= ENEED) {
    prep_xpad<<<8 * 4 * 66, 256, 0, stream>>>(x, xpad);
    invo_fused_dma<<<2048, 256, 0, stream>>>(xpad, pack, b12, out);
  } else {
    invo_fused<<<2048, 256, 0, stream>>>(x, pack, b12, out);
  }
}

// Round 9
// 110.097 us; speedup vs baseline: 1.0621x; 1.0621x over previous
//
#include <hip/hip_runtime.h>

namespace {
constexpr int XP = 264;        // f16 pixel pitch (33 chunks of 16B, ch 256..263 zero pad)
constexpr int XRr = 34 * XP;   // halo row pitch: 34 px (32 + 2 w-halo)
constexpr int EWP = 148;       // ew pixel pitch (floats)

typedef _Float16 h2 __attribute__((ext_vector_type(2)));
typedef _Float16 h8 __attribute__((ext_vector_type(8)));
typedef float f32x4 __attribute__((ext_vector_type(4)));

__device__ __forceinline__ h2 pkrtz(float a, float b) {
  return __builtin_bit_cast(h2, __builtin_amdgcn_cvt_pkrtz(a, b));
}

#if __has_builtin(__builtin_amdgcn_fdot2)
#define HAS_FDOT2 1
#else
#define HAS_FDOT2 0
#endif

// ---- prep: W12 = W1*W2 packed in f16 B-frag order, b12 = b1*W2 + b2 ----
__global__ __launch_bounds__(256) void prep_w12(
    const float* __restrict__ W1, const float* __restrict__ b1,
    const float* __restrict__ W2, const float* __restrict__ b2,
    _Float16* __restrict__ pack, float* __restrict__ b12)
{
  const int t = threadIdx.x;
  const int T = blockIdx.x;
  if (T < 9) {
    __shared__ float sw2[64 * 16];
    for (int i = t; i < 1024; i += 256) {
      int d = i >> 4, n = i & 15;
      sw2[i] = W2[d * 144 + T * 16 + n];
    }
    __syncthreads();
    const int c = t;
    float acc[16];
#pragma unroll
    for (int n = 0; n < 16; ++n) acc[n] = 0.f;
    for (int d = 0; d < 64; d += 4) {
      float4 w1 = *(const float4*)(W1 + c * 64 + d);
#pragma unroll
      for (int dd = 0; dd < 4; ++dd) {
        float a = (dd == 0) ? w1.x : (dd == 1) ? w1.y : (dd == 2) ? w1.z : w1.w;
        const float* r = &sw2[(d + dd) * 16];
#pragma unroll
        for (int n = 0; n < 16; ++n) acc[n] += a * r[n];
      }
    }
    int s = c >> 5, q = (c >> 3) & 3, j = c & 7;
#pragma unroll
    for (int n = 0; n < 16; ++n)
      pack[(((T * 8 + s) * 64 + q * 16 + n) << 3) + j] = (_Float16)acc[n];
  } else if (t < 144) {
    float bb = b2[t];
    for (int d = 0; d < 64; ++d) bb += b1[d] * W2[d * 144 + t];
    b12[t] = bb;
  }
}

// ---- fused: 32 px/block, 512 threads; B-prefetch; loads-first staging ----
__global__ __launch_bounds__(512, 4) void invo_fused(
    const float* __restrict__ x,
    const _Float16* __restrict__ pack,
    const float* __restrict__ b12g,
    float* __restrict__ out)
{
  __shared__ __align__(16) _Float16 xg[3 * XRr];   // 53,856 B f16 halo [row][px 0..33][ch]
  __shared__ float ew[32 * EWP];                   // 18,944 B fp32 e-weights [p][144]

  const int t = threadIdx.x;
  const int blk = blockIdx.x;               // XCD swizzle: b = blk & 7
  const int b = blk & 7;
  const int r_ = blk >> 3;
  const int strip = r_ & 1;
  const int h = r_ >> 1;
  const int w0 = strip * 32;
  const int pix0 = ((b << 6) + h) * 64 + w0;
  const int wave = t >> 6, lane = t & 63;
  const int wv = wave >> 1, ph = wave & 1;  // T-quarter, pixel-half

  // ---- B prefetch for this wave's first T (independent of LDS; overlaps staging) ----
  h8 Bpre[8];
  {
    const h8* bp = (const h8*)pack + (wv * 8) * 64 + lane;
#pragma unroll
    for (int s = 0; s < 8; ++s) Bpre[s] = bp[s * 64];
  }

  // ---- stage 3 halo rows x 34 px x 256 ch, fp32 -> f16; 3264 chunks, 2 passes ----
  {
    float4 va[3][2];
    int dsta[3];
#pragma unroll
    for (int i = 0; i < 3; ++i) {
      int idx = i * 512 + t;
      int cc = idx & 31, pj = idx >> 5;
      int r = (pj >= 68) ? 2 : (pj >= 34 ? 1 : 0);
      int j = pj - 34 * r;
      int hh = h + r - 1, ww = w0 + j - 1;
      dsta[i] = r * XRr + j * XP + cc * 8;
      va[i][0] = make_float4(0.f, 0.f, 0.f, 0.f);
      va[i][1] = make_float4(0.f, 0.f, 0.f, 0.f);
      if (((unsigned)hh < 64u) && ((unsigned)ww < 64u)) {
        const float* src = x + ((((b << 6) + hh) << 6) + ww) * 256 + cc * 8;
        va[i][0] = *(const float4*)(src);
        va[i][1] = *(const float4*)(src + 4);
      }
    }
#pragma unroll
    for (int i = 0; i < 3; ++i) {
      uint4 o;
      o.x = __builtin_bit_cast(unsigned, pkrtz(va[i][0].x, va[i][0].y));
      o.y = __builtin_bit_cast(unsigned, pkrtz(va[i][0].z, va[i][0].w));
      o.z = __builtin_bit_cast(unsigned, pkrtz(va[i][1].x, va[i][1].y));
      o.w = __builtin_bit_cast(unsigned, pkrtz(va[i][1].z, va[i][1].w));
      *(uint4*)(&xg[dsta[i]]) = o;
    }
    float4 vb[4][2];
    int dstb[4];
    bool okb[4];
#pragma unroll
    for (int i = 0; i < 4; ++i) {
      int idx = (i + 3) * 512 + t;
      okb[i] = idx < 3264;
      int cc = idx & 31, pj = idx >> 5;
      int r = (pj >= 68) ? 2 : (pj >= 34 ? 1 : 0);
      int j = pj - 34 * r;
      int hh = h + r - 1, ww = w0 + j - 1;
      dstb[i] = r * XRr + j * XP + cc * 8;
      vb[i][0] = make_float4(0.f, 0.f, 0.f, 0.f);
      vb[i][1] = make_float4(0.f, 0.f, 0.f, 0.f);
      if (okb[i] && ((unsigned)hh < 64u) && ((unsigned)ww < 64u)) {
        const float* src = x + ((((b << 6) + hh) << 6) + ww) * 256 + cc * 8;
        vb[i][0] = *(const float4*)(src);
        vb[i][1] = *(const float4*)(src + 4);
      }
    }
#pragma unroll
    for (int i = 0; i < 4; ++i) {
      if (okb[i]) {
        uint4 o;
        o.x = __builtin_bit_cast(unsigned, pkrtz(vb[i][0].x, vb[i][0].y));
        o.y = __builtin_bit_cast(unsigned, pkrtz(vb[i][0].z, vb[i][0].w));
        o.z = __builtin_bit_cast(unsigned, pkrtz(vb[i][1].x, vb[i][1].y));
        o.w = __builtin_bit_cast(unsigned, pkrtz(vb[i][1].z, vb[i][1].w));
        *(uint4*)(&xg[dstb[i]]) = o;
      }
    }
  }
  __syncthreads();

  // ---- GEMM via MFMA: e[p][e] = b12[e] + sum_c x[p][c]*W12[c][e] ----
  {
    const int q = lane >> 4, m = lane & 15;
    h8 A[8];
    const _Float16* arow = &xg[XRr + (ph * 16 + m + 1) * XP + q * 8];
#pragma unroll
    for (int s = 0; s < 8; ++s)
      A[s] = *(const h8*)(arow + s * 32);
    // first T from prefetched B
    {
      const int T = wv;
      f32x4 acc = {0.f, 0.f, 0.f, 0.f};
#pragma unroll
      for (int s = 0; s < 8; ++s)
        acc = __builtin_amdgcn_mfma_f32_16x16x32_f16(A[s], Bpre[s], acc, 0, 0, 0);
      float bb = b12g[T * 16 + m];
#pragma unroll
      for (int r = 0; r < 4; ++r)
        ew[(ph * 16 + q * 4 + r) * EWP + T * 16 + m] = acc[r] + bb;
    }
    for (int T = wv + 4; T < 9; T += 4) {
      f32x4 acc = {0.f, 0.f, 0.f, 0.f};
      const h8* bp = (const h8*)pack + (T * 8) * 64 + lane;
#pragma unroll
      for (int s = 0; s < 8; ++s)
        acc = __builtin_amdgcn_mfma_f32_16x16x32_f16(A[s], bp[s * 64], acc, 0, 0, 0);
      float bb = b12g[T * 16 + m];
#pragma unroll
      for (int r = 0; r < 4; ++r)
        ew[(ph * 16 + q * 4 + r) * EWP + T * 16 + m] = acc[r] + bb;
    }
  }
  __syncthreads();

  // ---- involution: thread=(p 0..31, g); 18x ds_read_b128 + dot2 ----
  {
    const int p = t >> 4, g = t & 15;
    float ewr[9];
#pragma unroll
    for (int k = 0; k < 9; ++k) ewr[k] = ew[p * EWP + g * 9 + k];
    h2 wp[8];
#pragma unroll
    for (int m = 0; m < 8; ++m)
      wp[m] = pkrtz(ewr[m], ewr[m + 1]);
    const float w8 = ewr[8], wb0 = ewr[0];
    const int g144 = g * 144;
    const int pbase = p * XP;
    float res[16];
#pragma unroll
    for (int gc = 0; gc < 16; ++gc) res[gc] = 0.f;
#pragma unroll
    for (int j = 0; j < 18; ++j) {
      int f = g144 + j * 8;
      int tap = f >> 8;                     // constant within the 8-chunk
      int ch = f & 255;
      int di = (tap * 86) >> 8;             // tap/3
      int off = XP * (tap + 31 * di) + ch;  // di*XRr + (tap-3di)*XP + ch
      uint4 dv = *(const uint4*)(&xg[pbase + off]);
      h2 v[4];
      v[0] = __builtin_bit_cast(h2, dv.x);
      v[1] = __builtin_bit_cast(h2, dv.y);
      v[2] = __builtin_bit_cast(h2, dv.z);
      v[3] = __builtin_bit_cast(h2, dv.w);
#pragma unroll
      for (int i = 0; i < 4; ++i) {
        const int u = j * 8 + 2 * i;        // compile-time
        const int m = u % 9;
        if (m == 8) {                       // pair crosses gc boundary
          res[u / 9]     += (float)v[i][0] * w8;
          res[u / 9 + 1] += (float)v[i][1] * wb0;
        } else {
#if HAS_FDOT2
          res[u / 9] = __builtin_amdgcn_fdot2(v[i], wp[m], res[u / 9], false);
#else
          res[u / 9] += (float)v[i][0] * ewr[m] + (float)v[i][1] * ewr[m + 1];
#endif
        }
      }
    }
    float* orow = out + (size_t)(pix0 + p) * 256 + (g << 4);
    *(float4*)(orow + 0)  = make_float4(res[0],  res[1],  res[2],  res[3]);
    *(float4*)(orow + 4)  = make_float4(res[4],  res[5],  res[6],  res[7]);
    *(float4*)(orow + 8)  = make_float4(res[8],  res[9],  res[10], res[11]);
    *(float4*)(orow + 12) = make_float4(res[12], res[13], res[14], res[15]);
  }
}
} // namespace

extern "C" void kernel_launch(void* const* d_in, const int* in_sizes, int n_in,
                              void* d_out, int out_size, void* d_ws, size_t ws_size,
                              hipStream_t stream) {
  const float* x  = (const float*)d_in[0];
  const float* W1 = (const float*)d_in[1];
  const float* b1 = (const float*)d_in[2];
  const float* W2 = (const float*)d_in[3];
  const float* b2 = (const float*)d_in[4];
  float* out = (float*)d_out;
  _Float16* pack = (_Float16*)d_ws;                        // 73,728 B
  float* b12 = (float*)((char*)d_ws + 73728);              // 576 B
  prep_w12<<<10, 256, 0, stream>>>(W1, b1, W2, b2, pack, b12);
  invo_fused<<<1024, 512, 0, stream>>>(x, pack, b12, out);
}

// Round 10
// 109.818 us; speedup vs baseline: 1.0648x; 1.0025x over previous
//
#include <hip/hip_runtime.h>

namespace {
constexpr int XP = 264;        // f16 pixel pitch (33 chunks of 16B, ch 256..263 zero pad)
constexpr int XR = 18 * XP;    // halo row pitch (18 px: 16 + 2 w-halo)
constexpr int EWP = 148;       // ew pixel pitch (floats)

typedef _Float16 h2 __attribute__((ext_vector_type(2)));
typedef _Float16 h8 __attribute__((ext_vector_type(8)));
typedef float f32x4 __attribute__((ext_vector_type(4)));

__device__ __forceinline__ h2 pkrtz(float a, float b) {
  return __builtin_bit_cast(h2, __builtin_amdgcn_cvt_pkrtz(a, b));
}

#if __has_builtin(__builtin_amdgcn_fdot2)
#define HAS_FDOT2 1
#else
#define HAS_FDOT2 0
#endif

// ---- prep: W12 = W1*W2 packed in f16 B-frag order, b12 = b1*W2 + b2 ----
__global__ __launch_bounds__(256) void prep_w12(
    const float* __restrict__ W1, const float* __restrict__ b1,
    const float* __restrict__ W2, const float* __restrict__ b2,
    _Float16* __restrict__ pack, float* __restrict__ b12)
{
  const int t = threadIdx.x;
  const int T = blockIdx.x;
  if (T < 9) {
    __shared__ float sw2[64 * 16];
    for (int i = t; i < 1024; i += 256) {
      int d = i >> 4, n = i & 15;
      sw2[i] = W2[d * 144 + T * 16 + n];
    }
    __syncthreads();
    const int c = t;
    float acc[16];
#pragma unroll
    for (int n = 0; n < 16; ++n) acc[n] = 0.f;
    for (int d = 0; d < 64; d += 4) {
      float4 w1 = *(const float4*)(W1 + c * 64 + d);
#pragma unroll
      for (int dd = 0; dd < 4; ++dd) {
        float a = (dd == 0) ? w1.x : (dd == 1) ? w1.y : (dd == 2) ? w1.z : w1.w;
        const float* r = &sw2[(d + dd) * 16];
#pragma unroll
        for (int n = 0; n < 16; ++n) acc[n] += a * r[n];
      }
    }
    int s = c >> 5, q = (c >> 3) & 3, j = c & 7;
#pragma unroll
    for (int n = 0; n < 16; ++n)
      pack[(((T * 8 + s) * 64 + q * 16 + n) << 3) + j] = (_Float16)acc[n];
  } else if (t < 144) {
    float bb = b2[t];
    for (int d = 0; d < 64; ++d) bb += b1[d] * W2[d * 144 + t];
    b12[t] = bb;
  }
}

// ---- fused: TPX=16, 256 thr, 4 blocks/CU; batched staging + B-prefetch ----
__global__ __launch_bounds__(256, 4) void invo_fused(
    const float* __restrict__ x,
    const _Float16* __restrict__ pack,
    const float* __restrict__ b12g,
    float* __restrict__ out)
{
  __shared__ __align__(16) _Float16 xg[3 * XR];   // 28,512 B f16 halo [row][px][ch]
  __shared__ float ew[16 * EWP];                  //  9,472 B fp32 e-weights [p][144]
                                                  // 37,984 B -> 4 blocks/CU

  const int t = threadIdx.x;
  const int blk = blockIdx.x;               // XCD swizzle: b = blk & 7
  const int b = blk & 7;
  const int r_ = blk >> 3;
  const int strip = r_ & 3;
  const int h = r_ >> 2;
  const int w0 = strip * 16;
  const int pix0 = ((b << 6) + h) * 64 + w0;
  const int wave = t >> 6, lane = t & 63;

  // ---- B prefetch for this wave's first T (independent of LDS; overlaps staging) ----
  h8 Bpre[8];
  {
    const h8* bp = (const h8*)pack + (wave * 8) * 64 + lane;
#pragma unroll
    for (int s = 0; s < 8; ++s) Bpre[s] = bp[s * 64];
  }

  // ---- stage 3 rows x 18 px x 256 ch fp32 -> f16; 1728 chunks, ALL loads first ----
  {
    float4 va[7][2];
    int dst[7];
    bool ok[7];
#pragma unroll
    for (int i = 0; i < 7; ++i) {
      int idx = i * 256 + t;
      ok[i] = idx < 1728;
      int cc = idx & 31;                    // 16B chunk within pixel (0..31)
      int pj = idx >> 5;                    // 0..53
      int r = (pj >= 36) ? 2 : (pj >= 18 ? 1 : 0);
      int j = pj - r * 18;
      int hh = h + r - 1, ww = w0 + j - 1;
      dst[i] = r * XR + j * XP + cc * 8;
      va[i][0] = make_float4(0.f, 0.f, 0.f, 0.f);
      va[i][1] = make_float4(0.f, 0.f, 0.f, 0.f);
      if (ok[i] && ((unsigned)hh < 64u) && ((unsigned)ww < 64u)) {
        const float* src = x + ((((b << 6) + hh) << 6) + ww) * 256 + cc * 8;
        va[i][0] = *(const float4*)(src);
        va[i][1] = *(const float4*)(src + 4);
      }
    }
#pragma unroll
    for (int i = 0; i < 7; ++i) {
      if (ok[i]) {
        uint4 o;
        o.x = __builtin_bit_cast(unsigned, pkrtz(va[i][0].x, va[i][0].y));
        o.y = __builtin_bit_cast(unsigned, pkrtz(va[i][0].z, va[i][0].w));
        o.z = __builtin_bit_cast(unsigned, pkrtz(va[i][1].x, va[i][1].y));
        o.w = __builtin_bit_cast(unsigned, pkrtz(va[i][1].z, va[i][1].w));
        *(uint4*)(&xg[dst[i]]) = o;
      }
    }
  }
  __syncthreads();

  // ---- GEMM via MFMA: e[p][e] = b12[e] + sum_c x[p][c] * W12[c][e] ----
  {
    const int q = lane >> 4, m = lane & 15;
    h8 A[8];
    const _Float16* arow = &xg[XR + (m + 1) * XP + q * 8];
#pragma unroll
    for (int s = 0; s < 8; ++s)
      A[s] = *(const h8*)(arow + s * 32);
    {   // first T from prefetched B
      const int T = wave;
      f32x4 acc = {0.f, 0.f, 0.f, 0.f};
#pragma unroll
      for (int s = 0; s < 8; ++s)
        acc = __builtin_amdgcn_mfma_f32_16x16x32_f16(A[s], Bpre[s], acc, 0, 0, 0);
      float bb = b12g[T * 16 + m];
#pragma unroll
      for (int r = 0; r < 4; ++r)
        ew[(q * 4 + r) * EWP + T * 16 + m] = acc[r] + bb;
    }
    for (int T = wave + 4; T < 9; T += 4) {
      f32x4 acc = {0.f, 0.f, 0.f, 0.f};
      const h8* bp = (const h8*)pack + (T * 8) * 64 + lane;
#pragma unroll
      for (int s = 0; s < 8; ++s)
        acc = __builtin_amdgcn_mfma_f32_16x16x32_f16(A[s], bp[s * 64], acc, 0, 0, 0);
      float bb = b12g[T * 16 + m];
#pragma unroll
      for (int r = 0; r < 4; ++r)
        ew[(q * 4 + r) * EWP + T * 16 + m] = acc[r] + bb;
    }
  }
  __syncthreads();

  // ---- involution: thread=(p,g); 18x ds_read_b128 + dot2 ----
  {
    const int p = t >> 4, g = t & 15;
    float ewr[9];
#pragma unroll
    for (int k = 0; k < 9; ++k) ewr[k] = ew[p * EWP + g * 9 + k];
    h2 wp[8];
#pragma unroll
    for (int m = 0; m < 8; ++m)
      wp[m] = pkrtz(ewr[m], ewr[m + 1]);
    const float w8 = ewr[8], wb0 = ewr[0];
    const int g144 = g * 144;
    const int pbase = p * XP;
    float res[16];
#pragma unroll
    for (int gc = 0; gc < 16; ++gc) res[gc] = 0.f;
#pragma unroll
    for (int j = 0; j < 18; ++j) {
      int f = g144 + j * 8;
      int tap = f >> 8;                     // constant within the 8-chunk
      int ch = f & 255;
      int di = (tap * 86) >> 8;             // tap/3
      int off = XP * (tap + 15 * di) + ch;  // di*XR + (tap-3di)*XP + ch
      uint4 dv = *(const uint4*)(&xg[pbase + off]);
      h2 v[4];
      v[0] = __builtin_bit_cast(h2, dv.x);
      v[1] = __builtin_bit_cast(h2, dv.y);
      v[2] = __builtin_bit_cast(h2, dv.z);
      v[3] = __builtin_bit_cast(h2, dv.w);
#pragma unroll
      for (int i = 0; i < 4; ++i) {
        const int u = j * 8 + 2 * i;        // compile-time
        const int m = u % 9;
        if (m == 8) {                       // pair crosses gc boundary
          res[u / 9]     += (float)v[i][0] * w8;
          res[u / 9 + 1] += (float)v[i][1] * wb0;
        } else {
#if HAS_FDOT2
          res[u / 9] = __builtin_amdgcn_fdot2(v[i], wp[m], res[u / 9], false);
#else
          res[u / 9] += (float)v[i][0] * ewr[m] + (float)v[i][1] * ewr[m + 1];
#endif
        }
      }
    }
    float* orow = out + (size_t)(pix0 + p) * 256 + (g << 4);
    *(float4*)(orow + 0)  = make_float4(res[0],  res[1],  res[2],  res[3]);
    *(float4*)(orow + 4)  = make_float4(res[4],  res[5],  res[6],  res[7]);
    *(float4*)(orow + 8)  = make_float4(res[8],  res[9],  res[10], res[11]);
    *(float4*)(orow + 12) = make_float4(res[12], res[13], res[14], res[15]);
  }
}
} // namespace

extern "C" void kernel_launch(void* const* d_in, const int* in_sizes, int n_in,
                              void* d_out, int out_size, void* d_ws, size_t ws_size,
                              hipStream_t stream) {
  const float* x  = (const float*)d_in[0];
  const float* W1 = (const float*)d_in[1];
  const float* b1 = (const float*)d_in[2];
  const float* W2 = (const float*)d_in[3];
  const float* b2 = (const float*)d_in[4];
  float* out = (float*)d_out;
  _Float16* pack = (_Float16*)d_ws;                        // 73,728 B
  float* b12 = (float*)((char*)d_ws + 73728);              // 576 B
  prep_w12<<<10, 256, 0, stream>>>(W1, b1, W2, b2, pack, b12);
  invo_fused<<<2048, 256, 0, stream>>>(x, pack, b12, out);
}